// Round 6
// baseline (145.437 us; speedup 1.0000x reference)
//
#include <hip/hip_runtime.h>

// focal_loss scalar reduction:
//   out = COEF * sum_i [ idx==0 ? log(p_i) : idx==1 ? log1p(-p_i) : 0 ]
//
// R1-R5 evidence: VGPR-return reads pin at ~3.0 TB/s (4.8 B/cy/CU) across
// every code shape, cold AND L3-warm; meanwhile write-only fill hits 6.6 TB/s
// and m97's global_load_lds staging sustained ~44 B/cy/CU. Diagnosis: per-CU
// L1/TCP miss-queue (~2.4 KB in flight) caps the VGPR-return read path.
// R6: stage through the LDS-DMA path (global_load_lds, width=16), per-wave
// private tiles, no block barriers. 32 waves/CU x 4 KB outstanding >> 2.4 KB.

static constexpr int BLOCK  = 256;        // 4 waves
static constexpr int GRID   = 2048;
static constexpr int TILE_E = 2048;       // elems per block-iter (8 KB p + 8 KB idx)
static constexpr int FITERS = 4;          // GRID*TILE_E*FITERS == 16777216 exactly
static constexpr float COEF = 0.004f;     // WF * (1-0.8)^2
static constexpr float LN2  = 0.69314718055994530942f;

typedef float fvec4 __attribute__((ext_vector_type(4)));
typedef int   ivec4 __attribute__((ext_vector_type(4)));

typedef const __attribute__((address_space(1))) unsigned int gu32;
typedef __attribute__((address_space(3))) unsigned int lu32;

__device__ __forceinline__ float sel_log2(float pv, int iv) {
    return __log2f((iv == 0) ? pv : 1.0f - pv);
}

__global__ __launch_bounds__(BLOCK) void fl_partial(
    const float* __restrict__ p,
    const int*   __restrict__ idx,
    float*       __restrict__ partials,
    int n)
{
    __shared__ float pbuf[TILE_E];   // 8 KB
    __shared__ int   ibuf[TILE_E];   // 8 KB  -> 16 KB/block, LDS allows 8 blocks/CU
    const int lane = threadIdx.x & 63;
    const int wave = threadIdx.x >> 6;

    float acc = 0.0f;

    if (n == GRID * TILE_E * FITERS) {
        // Fast path: per-wave private 512-elem slices; 4 x 1KB DMAs per iter.
        const int woff = wave * 512;             // wave's elem offset inside tile
        for (int t = 0; t < FITERS; ++t) {
            const long tile_base = ((long)t * GRID + blockIdx.x) * TILE_E;
#pragma unroll
            for (int c = 0; c < 2; ++c) {
                const long e  = tile_base + woff + c * 256 + lane * 4;
                const int  le = woff + c * 256 + lane * 4;
                __builtin_amdgcn_global_load_lds((gu32*)(p   + e), (lu32*)(pbuf + le), 16, 0, 0);
                __builtin_amdgcn_global_load_lds((gu32*)(idx + e), (lu32*)(ibuf + le), 16, 0, 0);
            }
            __builtin_amdgcn_s_waitcnt(0);       // drain this wave's DMAs
#pragma unroll
            for (int c = 0; c < 2; ++c) {
                const int le = woff + c * 256 + lane * 4;
                fvec4 pv = *(const fvec4*)(pbuf + le);
                ivec4 iv = *(const ivec4*)(ibuf + le);
                acc += sel_log2(pv.x, iv.x);
                acc += sel_log2(pv.y, iv.y);
                acc += sel_log2(pv.z, iv.z);
                acc += sel_log2(pv.w, iv.w);
            }
        }
    } else {
        // Generic fallback (R5 structure, known-correct).
        const fvec4* __restrict__ p4 = reinterpret_cast<const fvec4*>(p);
        const ivec4* __restrict__ i4 = reinterpret_cast<const ivec4*>(idx);
        const int n4 = n >> 2;
        const int stride = GRID * BLOCK;
        for (int i = blockIdx.x * BLOCK + threadIdx.x; i < n4; i += stride) {
            fvec4 pv = __builtin_nontemporal_load(&p4[i]);
            ivec4 iv = __builtin_nontemporal_load(&i4[i]);
            acc += sel_log2(pv.x, iv.x);
            acc += sel_log2(pv.y, iv.y);
            acc += sel_log2(pv.z, iv.z);
            acc += sel_log2(pv.w, iv.w);
        }
        if (blockIdx.x == 0 && threadIdx.x == 0)
            for (int j = n4 << 2; j < n; ++j)
                acc += sel_log2(p[j], idx[j]);
    }

    // wave-64 butterfly reduce
    for (int off = 32; off > 0; off >>= 1)
        acc += __shfl_down(acc, off, 64);

    __shared__ float ws[BLOCK / 64];
    if (lane == 0) ws[wave] = acc;
    __syncthreads();
    if (threadIdx.x == 0)
        partials[blockIdx.x] = ws[0] + ws[1] + ws[2] + ws[3];
}

__global__ __launch_bounds__(BLOCK) void fl_final(
    const float* __restrict__ partials,
    float*       __restrict__ out)
{
    float acc = 0.0f;
    for (int i = threadIdx.x; i < GRID; i += BLOCK)
        acc += partials[i];
    for (int off = 32; off > 0; off >>= 1)
        acc += __shfl_down(acc, off, 64);

    __shared__ float ws[BLOCK / 64];
    const int lane = threadIdx.x & 63;
    const int wave = threadIdx.x >> 6;
    if (lane == 0) ws[wave] = acc;
    __syncthreads();
    if (threadIdx.x == 0)
        out[0] = (ws[0] + ws[1] + ws[2] + ws[3]) * (COEF * LN2);
}

extern "C" void kernel_launch(void* const* d_in, const int* in_sizes, int n_in,
                              void* d_out, int out_size, void* d_ws, size_t ws_size,
                              hipStream_t stream)
{
    const float* p   = (const float*)d_in[0];
    const int*   idx = (const int*)d_in[1];
    float* partials  = (float*)d_ws;      // GRID floats = 8 KB scratch
    const int n = in_sizes[0];

    fl_partial<<<GRID, BLOCK, 0, stream>>>(p, idx, partials, n);
    fl_final<<<1, BLOCK, 0, stream>>>(partials, (float*)d_out);
}

// Round 7
// 131.400 us; speedup vs baseline: 1.1068x; 1.1068x over previous
//
#include <hip/hip_runtime.h>

// focal_loss scalar reduction:
//   out = COEF * sum_i [ idx==0 ? log(p_i) : idx==1 ? log1p(-p_i) : 0 ]
//
// R1-R6 evidence: reads pin at ~3.2 TB/s via BOTH the VGPR-return path
// (plain/nt loads, 3 shapes) AND the LDS-DMA path (global_load_lds), cold
// and L3-warm, occupancy 8-65% -- while write-only fill does 6.6 TB/s and
// m13's copy did 3.15R+3.15W concurrently. R7 (last 2x hypothesis): if the
// read throttle is per-path credits, splitting the two input streams across
// the two paths (idx -> LDS-DMA, p -> nt VGPR loads, same wave, one drain)
// gives each path 1.6 TB/s of demand -> ~6 TB/s total. If it lands at ~42us
// again, the throttle is shared and ~3.2 TB/s read is this chip's ceiling.

static constexpr int BLOCK  = 256;        // 4 waves
static constexpr int GRID   = 2048;
static constexpr int TILE_E = 2048;       // elems per block-iter
static constexpr int FITERS = 4;          // GRID*TILE_E*FITERS == 16777216
static constexpr float COEF = 0.004f;     // WF * (1-0.8)^2
static constexpr float LN2  = 0.69314718055994530942f;

typedef float fvec4 __attribute__((ext_vector_type(4)));
typedef int   ivec4 __attribute__((ext_vector_type(4)));

typedef const __attribute__((address_space(1))) unsigned int gu32;
typedef __attribute__((address_space(3))) unsigned int lu32;

__device__ __forceinline__ float sel_log2(float pv, int iv) {
    return __log2f((iv == 0) ? pv : 1.0f - pv);
}

__global__ __launch_bounds__(BLOCK) void fl_partial(
    const float* __restrict__ p,
    const int*   __restrict__ idx,
    float*       __restrict__ partials,
    int n)
{
    __shared__ int ibuf[TILE_E];     // 8 KB/block -> LDS not occupancy-limiting
    const int lane = threadIdx.x & 63;
    const int wave = threadIdx.x >> 6;

    float acc = 0.0f;

    if (n == GRID * TILE_E * FITERS) {
        // Per-wave private 512-elem slices; idx via LDS-DMA, p via nt VGPR.
        const int woff = wave * 512;
        for (int t = 0; t < FITERS; ++t) {
            const long tile_base = ((long)t * GRID + blockIdx.x) * TILE_E;
            // idx: 2 x 1KB DMAs into LDS (wave-uniform base + lane*16)
#pragma unroll
            for (int c = 0; c < 2; ++c) {
                const long e  = tile_base + woff + c * 256 + lane * 4;
                const int  le = woff + c * 256 + lane * 4;
                __builtin_amdgcn_global_load_lds((gu32*)(idx + e), (lu32*)(ibuf + le), 16, 0, 0);
            }
            // p: 2 x nontemporal dwordx4 into VGPRs (same element range)
            const fvec4* pb = (const fvec4*)(p + tile_base + woff);
            fvec4 pv0 = __builtin_nontemporal_load(pb + lane);
            fvec4 pv1 = __builtin_nontemporal_load(pb + 64 + lane);
            __builtin_amdgcn_s_waitcnt(0);   // drain DMA (and covers pv deps)
            ivec4 iv0 = *(const ivec4*)(ibuf + woff + lane * 4);
            ivec4 iv1 = *(const ivec4*)(ibuf + woff + 256 + lane * 4);
            acc += sel_log2(pv0.x, iv0.x);
            acc += sel_log2(pv0.y, iv0.y);
            acc += sel_log2(pv0.z, iv0.z);
            acc += sel_log2(pv0.w, iv0.w);
            acc += sel_log2(pv1.x, iv1.x);
            acc += sel_log2(pv1.y, iv1.y);
            acc += sel_log2(pv1.z, iv1.z);
            acc += sel_log2(pv1.w, iv1.w);
        }
    } else {
        // Generic fallback (R5 structure, known-correct).
        const fvec4* __restrict__ p4 = reinterpret_cast<const fvec4*>(p);
        const ivec4* __restrict__ i4 = reinterpret_cast<const ivec4*>(idx);
        const int n4 = n >> 2;
        const int stride = GRID * BLOCK;
        for (int i = blockIdx.x * BLOCK + threadIdx.x; i < n4; i += stride) {
            fvec4 pv = __builtin_nontemporal_load(&p4[i]);
            ivec4 iv = __builtin_nontemporal_load(&i4[i]);
            acc += sel_log2(pv.x, iv.x);
            acc += sel_log2(pv.y, iv.y);
            acc += sel_log2(pv.z, iv.z);
            acc += sel_log2(pv.w, iv.w);
        }
        if (blockIdx.x == 0 && threadIdx.x == 0)
            for (int j = n4 << 2; j < n; ++j)
                acc += sel_log2(p[j], idx[j]);
    }

    // wave-64 butterfly reduce
    for (int off = 32; off > 0; off >>= 1)
        acc += __shfl_down(acc, off, 64);

    __shared__ float ws[BLOCK / 64];
    if (lane == 0) ws[wave] = acc;
    __syncthreads();
    if (threadIdx.x == 0)
        partials[blockIdx.x] = ws[0] + ws[1] + ws[2] + ws[3];
}

__global__ __launch_bounds__(BLOCK) void fl_final(
    const float* __restrict__ partials,
    float*       __restrict__ out)
{
    float acc = 0.0f;
    for (int i = threadIdx.x; i < GRID; i += BLOCK)
        acc += partials[i];
    for (int off = 32; off > 0; off >>= 1)
        acc += __shfl_down(acc, off, 64);

    __shared__ float ws[BLOCK / 64];
    const int lane = threadIdx.x & 63;
    const int wave = threadIdx.x >> 6;
    if (lane == 0) ws[wave] = acc;
    __syncthreads();
    if (threadIdx.x == 0)
        out[0] = (ws[0] + ws[1] + ws[2] + ws[3]) * (COEF * LN2);
}

extern "C" void kernel_launch(void* const* d_in, const int* in_sizes, int n_in,
                              void* d_out, int out_size, void* d_ws, size_t ws_size,
                              hipStream_t stream)
{
    const float* p   = (const float*)d_in[0];
    const int*   idx = (const int*)d_in[1];
    float* partials  = (float*)d_ws;      // GRID floats = 8 KB scratch
    const int n = in_sizes[0];

    fl_partial<<<GRID, BLOCK, 0, stream>>>(p, idx, partials, n);
    fl_final<<<1, BLOCK, 0, stream>>>(partials, (float*)d_out);
}